// Round 18
// baseline (111.977 us; speedup 1.0000x reference)
//
#include <hip/hip_runtime.h>
#include <math.h>

// ---------------------------------------------------------------------------
// B=4096. conv1 (64,5,7) pad3 + relu + pool4 -> h1 (64,96)
//         conv2 (128,64,5) pad2 + relu + pool4 -> feat (128,24)
//         fc: only cols 0..5 of (404,3072) + tau = feat·(L_w@fc_w) + const.
// Precision: conv1 = 1-term fp16 (A=f16(input), B=f16(1024*w1));
// conv2 = 1-term fp16 (A=f16(h1), B=f16(1024*w2)); epilogues unscale 2^-10.
// Measured absmax 128 vs threshold 460.8.
// All MFMAs v_mfma_f32_32x32x16_f16.
// C/D (m74/m101): col=lane&31(oc), row=(reg&3)+8*(reg>>2)+4*(lane>>5) ->
// reg-quads = 4 consecutive pos -> pool4 in-register.
// R18: rollout FUSED into block tail (params[b] only depends on block b;
// thread 0 runs the 100-step recurrence, ~3.5us 1-wave tail overlapped
// across block rounds) -> one dispatch + gap + 16-CU kernel removed.
// Precompute fc7 16-way j-split (96 blocks x 32 cols, 26-long chains).
// ---------------------------------------------------------------------------

typedef _Float16 f16x8 __attribute__((ext_vector_type(8)));
typedef float f32x4  __attribute__((ext_vector_type(4)));
typedef float f32x16 __attribute__((ext_vector_type(16)));
typedef int   i32x4  __attribute__((ext_vector_type(4)));

union Frag { int u[4]; i32x4 q; f16x8 h; };
union H16 { _Float16 hf; unsigned short us; };

__device__ __forceinline__ unsigned short f16_rne(float f) {
    H16 c; c.hf = (_Float16)f; return c.us;
}

#define ZERO16 {0.f,0.f,0.f,0.f,0.f,0.f,0.f,0.f,0.f,0.f,0.f,0.f,0.f,0.f,0.f,0.f}

// ---------------------------------------------------------------------------
// Kernel 0 (512 thr, 107 blocks): fc7T (0..95), taub+wfrag1 (96),
// wfrag2 (97..106).
//  fc7T: [fq24][j8][oc128] f32; j0..5 = fc_w cols, j6 = L_w@fc_w, j7 = 0
//  wfrag1: [ks3][nt2][lane64][4u32] f16 of 1024*w1;
//          k'=ks*16+(lane>>5)*8+j -> ic=k'>>3, dk=k'&7 (ic==5 -> zero)
//  wfrag2: [step20][nt4][lane64][4u32] f16 of 1024*w2; step=dk*4+icc;
//          k_ic=icc*16+(lane>>5)*8+j
// ---------------------------------------------------------------------------
__global__ void precompute_kernel(const float* __restrict__ w1,
                                  const float* __restrict__ w2,
                                  const float* __restrict__ fc_w,
                                  const float* __restrict__ fc_b,
                                  const float* __restrict__ L_w,
                                  const float* __restrict__ L_b,
                                  float* __restrict__ fc7,
                                  float* __restrict__ taub,
                                  unsigned* __restrict__ wfrag1,
                                  unsigned* __restrict__ wfrag2) {
    const int t = threadIdx.x, bb = blockIdx.x;
    if (bb < 96) {
        __shared__ float part[15][32];
        const int k = bb * 32 + (t & 31), jc = t >> 5;       // jc 0..15
        const int j0 = jc * 26;
        float s = 0.f;
        #pragma unroll 8
        for (int j = j0; j < j0 + 26 && j < 404; ++j)
            s += L_w[j] * fc_w[j * 3072 + k];
        if (jc) part[jc - 1][t & 31] = s;
        __syncthreads();
        if (jc == 0) {
            const int kk = t & 31;
            const int oc = k / 24, fq = k - oc * 24;
            float r[8];
            #pragma unroll
            for (int j = 0; j < 6; ++j) r[j] = fc_w[j * 3072 + k];
            float tv = s;
            #pragma unroll
            for (int j = 0; j < 15; ++j) tv += part[j][kk];
            r[6] = tv; r[7] = 0.f;
            #pragma unroll
            for (int j = 0; j < 8; ++j) fc7[fq * 1024 + j * 128 + oc] = r[j];
        }
    } else if (bb == 96) {
        if (t < 64) {
            float s = 0.f;
            for (int j = t; j < 404; j += 64) s += L_w[j] * fc_b[j];
            #pragma unroll
            for (int off = 32; off; off >>= 1) s += __shfl_down(s, off);
            if (t == 0) taub[0] = s + L_b[0];
        }
        if (t < 384) {                              // conv1 frags (f16 1-term)
            const int lane = t & 63, nt = (t >> 6) & 1, ks = t >> 7;  // 0..2
            const int oc = nt * 32 + (lane & 31);
            unsigned short h[8];
            #pragma unroll
            for (int j = 0; j < 8; ++j) {
                const int kp = ks * 16 + (lane >> 5) * 8 + j;  // k' = ic*8+dk
                const int ic = kp >> 3, dk = kp & 7;
                const float v = (ic < 5 && dk < 7)
                              ? w1[oc * 35 + ic * 7 + dk] * 1024.0f : 0.f;
                h[j] = f16_rne(v);
            }
            #pragma unroll
            for (int wj = 0; wj < 4; ++wj)
                wfrag1[t * 4 + wj] = ((unsigned)h[2 * wj + 1] << 16) | h[2 * wj];
        }
    } else {                                        // conv2 frags: 5120 items
        const int i = (bb - 97) * 512 + t;
        const int lane = i & 63, nt = (i >> 6) & 3, step = i >> 8;   // 0..19
        const int oc = nt * 32 + (lane & 31);
        const int dk = step >> 2, icc = step & 3;
        unsigned short h[8];
        #pragma unroll
        for (int j = 0; j < 8; ++j) {
            const int ic = icc * 16 + (lane >> 5) * 8 + j;  // k = ic
            const float v = w2[oc * 320 + ic * 5 + dk] * 1024.0f;
            h[j] = f16_rne(v);
        }
        #pragma unroll
        for (int wj = 0; wj < 4; ++wj)
            wfrag2[i * 4 + wj] = ((unsigned)h[2 * wj + 1] << 16) | h[2 * wj];
    }
}

// ---------------------------------------------------------------------------
// Kernel 1: fused conv1+conv2+fc+ROLLOUT, one batch per block, 5 blocks/CU.
// LDS (22368 B): lds_in u32[5][392] = zero-extended f16(input) (halo zero),
//   h1f fp16[100][72] (rows 0,1,98,99 halo-zero), red f32[32].
// ---------------------------------------------------------------------------
__global__ __launch_bounds__(256, 5) void fused_kernel(
    const float* __restrict__ input,
    const float* __restrict__ b1,
    const float* __restrict__ b2,
    const unsigned* __restrict__ wfrag1,
    const unsigned* __restrict__ wfrag2,
    const float* __restrict__ fc7,
    const float* __restrict__ fc_b,
    const float* __restrict__ taubp,
    const float* __restrict__ y0,
    float* __restrict__ out)
{
    __shared__ unsigned lds_in[1960];                       // [5][392]
    __shared__ __align__(16) unsigned short h1f[7200];      // [100][72]
    __shared__ float red[32];

    const int t = threadIdx.x, b = blockIdx.x;
    const int lane = t & 63, w = t >> 6;
    const int lq = lane & 31, hi = lane >> 5;

    // ---- halo-only zeroing (disjoint from staging writes -> one barrier) --
    if (t < 40) {            // lds_in halos: cols 0..2, 387..391 x 5 rows
        const int r = t >> 3, c = t & 7;
        lds_in[r * 392 + ((c < 3) ? c : 384 + c)] = 0u;
    }
    if (t >= 64 && t < 208) {  // h1f halo rows 0,1,98,99 (144 words)
        const int i = t - 64;
        const int r = i / 36, wd = i - r * 36;
        const int row = (r < 2) ? r : 96 + r;
        ((unsigned*)h1f)[row * 36 + wd] = 0u;
    }
    // ---- stage input as zero-extended f16, float4 loads ----
    const float4* inb4 = (const float4*)(input + (size_t)b * 1920);
    for (int i = t; i < 480; i += 256) {
        const float4 v = inb4[i];
        const int x4 = i * 4, ic = x4 / 384, x = x4 - ic * 384;
        unsigned* dst = lds_in + ic * 392 + 3 + x;
        dst[0] = (unsigned)f16_rne(v.x);
        dst[1] = (unsigned)f16_rne(v.y);
        dst[2] = (unsigned)f16_rne(v.z);
        dst[3] = (unsigned)f16_rne(v.w);
    }
    __syncthreads();

    // ------------- conv1: C[pos=384][oc=64], K'=48 (3 ks of 16) -------------
    const i32x4* w1f = (const i32x4*)wfrag1;
    Frag c1b[3][2];                          // [ks][nt] — 24 VGPR
    #pragma unroll
    for (int ks = 0; ks < 3; ++ks)
        #pragma unroll
        for (int nt = 0; nt < 2; ++nt)
            c1b[ks][nt].q = w1f[(ks * 2 + nt) * 64 + lane];
    float b1v[2];
    #pragma unroll
    for (int nt = 0; nt < 2; ++nt) b1v[nt] = b1[nt * 32 + lq];

    unsigned pbuf[2][8];
    {   // prologue: (m=0, ks=0): ic = hi
        const unsigned* src = lds_in + hi * 392 + (w * 3) * 32 + lq;
        #pragma unroll
        for (int j = 0; j < 8; ++j) pbuf[0][j] = src[j];
    }
    #pragma unroll
    for (int m = 0; m < 3; ++m) {
        const int mtile = w * 3 + m;
        f32x16 acc0 = ZERO16, acc1 = ZERO16;
        #pragma unroll
        for (int ks = 0; ks < 3; ++ks) {
            const int it = m * 3 + ks, cur = it & 1, nxt = cur ^ 1;
            if (it < 8) {
                const int nit = it + 1, nm = nit / 3, nks = nit % 3;
                const int rowoff = (nks == 2) ? 4 * 392 : (nks * 2 + hi) * 392;
                const unsigned* src = lds_in + rowoff + (w * 3 + nm) * 32 + lq;
                #pragma unroll
                for (int j = 0; j < 8; ++j) pbuf[nxt][j] = src[j];
            }
            Frag af;
            #pragma unroll
            for (int wj = 0; wj < 4; ++wj)
                af.u[wj] = __builtin_amdgcn_perm(pbuf[cur][2*wj+1], pbuf[cur][2*wj], 0x05040100u);
            if (ks == 2) {     // ic = ks*2+hi = 5 for hi=1: virtual zero row
                #pragma unroll
                for (int wj = 0; wj < 4; ++wj) af.u[wj] = hi ? 0 : af.u[wj];
            }
            __builtin_amdgcn_s_setprio(1);
            acc0 = __builtin_amdgcn_mfma_f32_32x32x16_f16(af.h, c1b[ks][0].h, acc0, 0, 0, 0);
            acc1 = __builtin_amdgcn_mfma_f32_32x32x16_f16(af.h, c1b[ks][1].h, acc1, 0, 0, 0);
            __builtin_amdgcn_s_setprio(0);
        }
        // unscale 2^-10 + bias + relu + pool4 -> f16 write
        #pragma unroll
        for (int q = 0; q < 4; ++q) {
            const int c = mtile * 8 + 2 * q + hi;
            {
                float s = 0.f;
                #pragma unroll
                for (int r4 = 0; r4 < 4; ++r4)
                    s += fmaxf(acc0[q*4+r4] * 0.0009765625f + b1v[0], 0.f);
                h1f[(c + 2) * 72 + lq] = f16_rne(0.25f * s);
            }
            {
                float s = 0.f;
                #pragma unroll
                for (int r4 = 0; r4 < 4; ++r4)
                    s += fmaxf(acc1[q*4+r4] * 0.0009765625f + b1v[1], 0.f);
                h1f[(c + 2) * 72 + 32 + lq] = f16_rne(0.25f * s);
            }
        }
    }
    __syncthreads();

    // ------ conv2: 20 k-steps (dk*4+icc), wave = ntile w, mtiles 0..2 ------
    f32x16 acc2[3] = {ZERO16, ZERO16, ZERO16};

    const i32x4* aF = (const i32x4*)(h1f + lq * 72 + hi * 8);
    const i32x4* w2f = (const i32x4*)wfrag2;
    Frag b2b[3];                             // B 3-deep rotation
    Frag a2f[2][3];                          // per-step A block, dbuf

    {   // prologue: B(steps 0,1), A(step0, mt 0..2)
        b2b[0].q = w2f[w * 64 + lane];
        b2b[1].q = w2f[(4 + w) * 64 + lane];
        #pragma unroll
        for (int mt = 0; mt < 3; ++mt) a2f[0][mt].q = aF[mt * 288];
    }

    #pragma unroll
    for (int s = 0; s < 20; ++s) {
        const int sb = s % 3, ab = s & 1, an = ab ^ 1;
        if (s < 18)
            b2b[(s + 2) % 3].q = w2f[((s + 2) * 4 + w) * 64 + lane];
        if (s < 19) {
            const int dkn = (s + 1) >> 2, iccn = (s + 1) & 3;
            #pragma unroll
            for (int mt = 0; mt < 3; ++mt)
                a2f[an][mt].q = aF[(mt * 32 + dkn) * 9 + iccn * 2];
        }
        __builtin_amdgcn_s_setprio(1);
        #pragma unroll
        for (int mt = 0; mt < 3; ++mt)
            acc2[mt] = __builtin_amdgcn_mfma_f32_32x32x16_f16(a2f[ab][mt].h, b2b[sb].h, acc2[mt], 0, 0, 0);
        __builtin_amdgcn_s_setprio(0);
    }

    // ---- epilogue: unscale (2^-10) + bias + relu + pool4 -> feat; fc7T ----
    float dot[7] = {0.f, 0.f, 0.f, 0.f, 0.f, 0.f, 0.f};
    {
        const float b2v = b2[w * 32 + lq];
        #pragma unroll
        for (int mt = 0; mt < 3; ++mt) {
            #pragma unroll
            for (int q = 0; q < 4; ++q) {
                float s = 0.f;
                #pragma unroll
                for (int r4 = 0; r4 < 4; ++r4)
                    s += fmaxf(acc2[mt][q*4+r4] * 0.0009765625f + b2v, 0.f);
                s *= 0.25f;
                const int fq = mt * 8 + 2 * q + hi;
                const float* fp = fc7 + fq * 1024 + w * 32 + lq;
                float f[7];
                #pragma unroll
                for (int j = 0; j < 7; ++j) f[j] = fp[j * 128];
                #pragma unroll
                for (int j = 0; j < 7; ++j) dot[j] += s * f[j];
            }
        }
    }

    #pragma unroll
    for (int j = 0; j < 7; ++j) {
        float s = dot[j];
        #pragma unroll
        for (int off = 32; off; off >>= 1) s += __shfl_down(s, off);
        if (lane == 0) red[w * 8 + j] = s;
    }
    __syncthreads();

    // ---- fused rollout tail: thread 0 runs the 100-step recurrence ----
    if (t == 0) {
        float pv[7];
        #pragma unroll
        for (int j = 0; j < 7; ++j)
            pv[j] = red[j] + red[8 + j] + red[16 + j] + red[24 + j];
        const float goal = pv[0] + fc_b[0];
        const float w0p = pv[1] + fc_b[1];
        const float w1p = pv[2] + fc_b[2];
        const float w2p = pv[3] + fc_b[3];
        const float w3p = pv[4] + fc_b[4];
        const float w4p = pv[5] + fc_b[5];
        const float tau = pv[6] + taubp[0];
        const float y0v = y0[b];

        const float c0 = 1.0f;
        const float c1 = 0.77880078307140486825f;
        const float c2 = 0.60653065971263342360f;
        const float c3 = 0.47236655274101470714f;
        const float c4 = 0.36787944117144232160f;
        const float inv2s = -0.5f / 11.180339887498949f;
        const float e0 = inv2s * c0, e1 = inv2s * c1, e2 = inv2s * c2,
                    e3 = inv2s * c3, e4 = inv2s * c4;

        float x = 1.0f, y = y0v, z = 0.01f * tau;
        const float td = tau * 0.01f;
        const float gmy0 = goal - y0v;
        float* ob = out + (size_t)b * 101;
        ob[0] = y0v;
        for (int s = 1; s <= 100; ++s) {
            x = x - x * td;
            const float d0 = x - c0, d1 = x - c1, d2 = x - c2,
                        d3 = x - c3, d4 = x - c4;
            const float p0 = __expf(e0 * d0 * d0);
            const float p1 = __expf(e1 * d1 * d1);
            const float p2 = __expf(e2 * d2 * d2);
            const float p3 = __expf(e3 * d3 * d3);
            const float p4 = __expf(e4 * d4 * d4);
            const float den = p0 + p1 + p2 + p3 + p4;
            const float num = w0p * p0 + w1p * p1 + w2p * p2 + w3p * p3 + w4p * p4;
            const float fx = (num / den) * x * gmy0;
            const float dz = 25.0f * (6.25f * (goal - y) - z) + fx;
            const float dy = z;
            y += dy * td;
            z += dz * td;
            ob[s] = y;
        }
    }
}

extern "C" void kernel_launch(void* const* d_in, const int* in_sizes, int n_in,
                              void* d_out, int out_size, void* d_ws, size_t ws_size,
                              hipStream_t stream) {
    const float* input = (const float*)d_in[0];
    const float* y0    = (const float*)d_in[1];
    const float* w1    = (const float*)d_in[2];
    const float* b1    = (const float*)d_in[3];
    const float* w2    = (const float*)d_in[4];
    const float* b2    = (const float*)d_in[5];
    const float* fc_w  = (const float*)d_in[6];
    const float* fc_b  = (const float*)d_in[7];
    const float* L_w   = (const float*)d_in[8];
    const float* L_b   = (const float*)d_in[9];
    float* out = (float*)d_out;

    float* ws      = (float*)d_ws;
    float* fc7     = ws;                          // 24576 f (fc7T layout)
    float* taub    = ws + 24576;                  // pad to 64
    unsigned* wfrag1 = (unsigned*)(ws + 24640);   // 1536 u32 (pad to 4096)
    unsigned* wfrag2 = wfrag1 + 4096;             // 20480 u32

    const int B = in_sizes[1];                    // 4096

    precompute_kernel<<<107, 512, 0, stream>>>(w1, w2, fc_w, fc_b, L_w, L_b,
                                               fc7, taub, wfrag1, wfrag2);
    fused_kernel<<<B, 256, 0, stream>>>(input, b1, b2, wfrag1, wfrag2,
                                        fc7, fc_b, taub, y0, out);
}

// Round 19
// 85.502 us; speedup vs baseline: 1.3096x; 1.3096x over previous
//
#include <hip/hip_runtime.h>
#include <math.h>

// ---------------------------------------------------------------------------
// B=4096. conv1 (64,5,7) pad3 + relu + pool4 -> h1 (64,96)
//         conv2 (128,64,5) pad2 + relu + pool4 -> feat (128,24)
//         fc: only cols 0..5 of (404,3072) + tau = feat·(L_w@fc_w) + const.
// Precision: conv1 = 1-term fp16 (A=f16(input), B=f16(1024*w1));
// conv2 = 1-term fp16 (A=f16(h1), B=f16(1024*w2)); epilogues unscale 2^-10.
// Measured absmax 128 vs threshold 460.8.
// All MFMAs v_mfma_f32_32x32x16_f16.
// C/D (m74/m101): col=lane&31(oc), row=(reg&3)+8*(reg>>2)+4*(lane>>5) ->
// reg-quads = 4 consecutive pos -> pool4 in-register.
// R19: REVERT R18's fused-rollout-tail (serial thread-0 chain stalled every
// block: 85->112us). Separate rollout kernel restored (R17 = best state).
// KEPT from R18: 16-way j-split precompute (96 blocks, 26-long chains).
// ---------------------------------------------------------------------------

typedef _Float16 f16x8 __attribute__((ext_vector_type(8)));
typedef float f32x4  __attribute__((ext_vector_type(4)));
typedef float f32x16 __attribute__((ext_vector_type(16)));
typedef int   i32x4  __attribute__((ext_vector_type(4)));

union Frag { int u[4]; i32x4 q; f16x8 h; };
union H16 { _Float16 hf; unsigned short us; };

__device__ __forceinline__ unsigned short f16_rne(float f) {
    H16 c; c.hf = (_Float16)f; return c.us;
}

#define ZERO16 {0.f,0.f,0.f,0.f,0.f,0.f,0.f,0.f,0.f,0.f,0.f,0.f,0.f,0.f,0.f,0.f}

// ---------------------------------------------------------------------------
// Kernel 0 (512 thr, 107 blocks): fc7T (0..95), taub+wfrag1 (96),
// wfrag2 (97..106).
//  fc7T: [fq24][j8][oc128] f32; j0..5 = fc_w cols, j6 = L_w@fc_w, j7 = 0
//  wfrag1: [ks3][nt2][lane64][4u32] f16 of 1024*w1;
//          k'=ks*16+(lane>>5)*8+j -> ic=k'>>3, dk=k'&7 (ic==5 -> zero)
//  wfrag2: [step20][nt4][lane64][4u32] f16 of 1024*w2; step=dk*4+icc;
//          k_ic=icc*16+(lane>>5)*8+j
// ---------------------------------------------------------------------------
__global__ void precompute_kernel(const float* __restrict__ w1,
                                  const float* __restrict__ w2,
                                  const float* __restrict__ fc_w,
                                  const float* __restrict__ fc_b,
                                  const float* __restrict__ L_w,
                                  const float* __restrict__ L_b,
                                  float* __restrict__ fc7,
                                  float* __restrict__ taub,
                                  unsigned* __restrict__ wfrag1,
                                  unsigned* __restrict__ wfrag2) {
    const int t = threadIdx.x, bb = blockIdx.x;
    if (bb < 96) {
        __shared__ float part[15][32];
        const int k = bb * 32 + (t & 31), jc = t >> 5;       // jc 0..15
        const int j0 = jc * 26;
        float s = 0.f;
        #pragma unroll 8
        for (int j = j0; j < j0 + 26 && j < 404; ++j)
            s += L_w[j] * fc_w[j * 3072 + k];
        if (jc) part[jc - 1][t & 31] = s;
        __syncthreads();
        if (jc == 0) {
            const int kk = t & 31;
            const int oc = k / 24, fq = k - oc * 24;
            float r[8];
            #pragma unroll
            for (int j = 0; j < 6; ++j) r[j] = fc_w[j * 3072 + k];
            float tv = s;
            #pragma unroll
            for (int j = 0; j < 15; ++j) tv += part[j][kk];
            r[6] = tv; r[7] = 0.f;
            #pragma unroll
            for (int j = 0; j < 8; ++j) fc7[fq * 1024 + j * 128 + oc] = r[j];
        }
    } else if (bb == 96) {
        if (t < 64) {
            float s = 0.f;
            for (int j = t; j < 404; j += 64) s += L_w[j] * fc_b[j];
            #pragma unroll
            for (int off = 32; off; off >>= 1) s += __shfl_down(s, off);
            if (t == 0) taub[0] = s + L_b[0];
        }
        if (t < 384) {                              // conv1 frags (f16 1-term)
            const int lane = t & 63, nt = (t >> 6) & 1, ks = t >> 7;  // 0..2
            const int oc = nt * 32 + (lane & 31);
            unsigned short h[8];
            #pragma unroll
            for (int j = 0; j < 8; ++j) {
                const int kp = ks * 16 + (lane >> 5) * 8 + j;  // k' = ic*8+dk
                const int ic = kp >> 3, dk = kp & 7;
                const float v = (ic < 5 && dk < 7)
                              ? w1[oc * 35 + ic * 7 + dk] * 1024.0f : 0.f;
                h[j] = f16_rne(v);
            }
            #pragma unroll
            for (int wj = 0; wj < 4; ++wj)
                wfrag1[t * 4 + wj] = ((unsigned)h[2 * wj + 1] << 16) | h[2 * wj];
        }
    } else {                                        // conv2 frags: 5120 items
        const int i = (bb - 97) * 512 + t;
        const int lane = i & 63, nt = (i >> 6) & 3, step = i >> 8;   // 0..19
        const int oc = nt * 32 + (lane & 31);
        const int dk = step >> 2, icc = step & 3;
        unsigned short h[8];
        #pragma unroll
        for (int j = 0; j < 8; ++j) {
            const int ic = icc * 16 + (lane >> 5) * 8 + j;  // k = ic
            const float v = w2[oc * 320 + ic * 5 + dk] * 1024.0f;
            h[j] = f16_rne(v);
        }
        #pragma unroll
        for (int wj = 0; wj < 4; ++wj)
            wfrag2[i * 4 + wj] = ((unsigned)h[2 * wj + 1] << 16) | h[2 * wj];
    }
}

// ---------------------------------------------------------------------------
// Kernel 1: fused conv1+conv2+fc, one batch per block, 5 blocks/CU.
// LDS (22368 B): lds_in u32[5][392] = zero-extended f16(input) (halo zero),
//   h1f fp16[100][72] (rows 0,1,98,99 halo-zero), red f32[32].
// ---------------------------------------------------------------------------
__global__ __launch_bounds__(256, 5) void fused_kernel(
    const float* __restrict__ input,
    const float* __restrict__ b1,
    const float* __restrict__ b2,
    const unsigned* __restrict__ wfrag1,
    const unsigned* __restrict__ wfrag2,
    const float* __restrict__ fc7,
    const float* __restrict__ fc_b,
    const float* __restrict__ taubp,
    float* __restrict__ params)
{
    __shared__ unsigned lds_in[1960];                       // [5][392]
    __shared__ __align__(16) unsigned short h1f[7200];      // [100][72]
    __shared__ float red[32];

    const int t = threadIdx.x, b = blockIdx.x;
    const int lane = t & 63, w = t >> 6;
    const int lq = lane & 31, hi = lane >> 5;

    // ---- halo-only zeroing (disjoint from staging writes -> one barrier) --
    if (t < 40) {            // lds_in halos: cols 0..2, 387..391 x 5 rows
        const int r = t >> 3, c = t & 7;
        lds_in[r * 392 + ((c < 3) ? c : 384 + c)] = 0u;
    }
    if (t >= 64 && t < 208) {  // h1f halo rows 0,1,98,99 (144 words)
        const int i = t - 64;
        const int r = i / 36, wd = i - r * 36;
        const int row = (r < 2) ? r : 96 + r;
        ((unsigned*)h1f)[row * 36 + wd] = 0u;
    }
    // ---- stage input as zero-extended f16, float4 loads ----
    const float4* inb4 = (const float4*)(input + (size_t)b * 1920);
    for (int i = t; i < 480; i += 256) {
        const float4 v = inb4[i];
        const int x4 = i * 4, ic = x4 / 384, x = x4 - ic * 384;
        unsigned* dst = lds_in + ic * 392 + 3 + x;
        dst[0] = (unsigned)f16_rne(v.x);
        dst[1] = (unsigned)f16_rne(v.y);
        dst[2] = (unsigned)f16_rne(v.z);
        dst[3] = (unsigned)f16_rne(v.w);
    }
    __syncthreads();

    // ------------- conv1: C[pos=384][oc=64], K'=48 (3 ks of 16) -------------
    const i32x4* w1f = (const i32x4*)wfrag1;
    Frag c1b[3][2];                          // [ks][nt] — 24 VGPR
    #pragma unroll
    for (int ks = 0; ks < 3; ++ks)
        #pragma unroll
        for (int nt = 0; nt < 2; ++nt)
            c1b[ks][nt].q = w1f[(ks * 2 + nt) * 64 + lane];
    float b1v[2];
    #pragma unroll
    for (int nt = 0; nt < 2; ++nt) b1v[nt] = b1[nt * 32 + lq];

    unsigned pbuf[2][8];
    {   // prologue: (m=0, ks=0): ic = hi
        const unsigned* src = lds_in + hi * 392 + (w * 3) * 32 + lq;
        #pragma unroll
        for (int j = 0; j < 8; ++j) pbuf[0][j] = src[j];
    }
    #pragma unroll
    for (int m = 0; m < 3; ++m) {
        const int mtile = w * 3 + m;
        f32x16 acc0 = ZERO16, acc1 = ZERO16;
        #pragma unroll
        for (int ks = 0; ks < 3; ++ks) {
            const int it = m * 3 + ks, cur = it & 1, nxt = cur ^ 1;
            if (it < 8) {
                const int nit = it + 1, nm = nit / 3, nks = nit % 3;
                const int rowoff = (nks == 2) ? 4 * 392 : (nks * 2 + hi) * 392;
                const unsigned* src = lds_in + rowoff + (w * 3 + nm) * 32 + lq;
                #pragma unroll
                for (int j = 0; j < 8; ++j) pbuf[nxt][j] = src[j];
            }
            Frag af;
            #pragma unroll
            for (int wj = 0; wj < 4; ++wj)
                af.u[wj] = __builtin_amdgcn_perm(pbuf[cur][2*wj+1], pbuf[cur][2*wj], 0x05040100u);
            if (ks == 2) {     // ic = ks*2+hi = 5 for hi=1: virtual zero row
                #pragma unroll
                for (int wj = 0; wj < 4; ++wj) af.u[wj] = hi ? 0 : af.u[wj];
            }
            __builtin_amdgcn_s_setprio(1);
            acc0 = __builtin_amdgcn_mfma_f32_32x32x16_f16(af.h, c1b[ks][0].h, acc0, 0, 0, 0);
            acc1 = __builtin_amdgcn_mfma_f32_32x32x16_f16(af.h, c1b[ks][1].h, acc1, 0, 0, 0);
            __builtin_amdgcn_s_setprio(0);
        }
        // unscale 2^-10 + bias + relu + pool4 -> f16 write
        #pragma unroll
        for (int q = 0; q < 4; ++q) {
            const int c = mtile * 8 + 2 * q + hi;
            {
                float s = 0.f;
                #pragma unroll
                for (int r4 = 0; r4 < 4; ++r4)
                    s += fmaxf(acc0[q*4+r4] * 0.0009765625f + b1v[0], 0.f);
                h1f[(c + 2) * 72 + lq] = f16_rne(0.25f * s);
            }
            {
                float s = 0.f;
                #pragma unroll
                for (int r4 = 0; r4 < 4; ++r4)
                    s += fmaxf(acc1[q*4+r4] * 0.0009765625f + b1v[1], 0.f);
                h1f[(c + 2) * 72 + 32 + lq] = f16_rne(0.25f * s);
            }
        }
    }
    __syncthreads();

    // ------ conv2: 20 k-steps (dk*4+icc), wave = ntile w, mtiles 0..2 ------
    f32x16 acc2[3] = {ZERO16, ZERO16, ZERO16};

    const i32x4* aF = (const i32x4*)(h1f + lq * 72 + hi * 8);
    const i32x4* w2f = (const i32x4*)wfrag2;
    Frag b2b[3];                             // B 3-deep rotation
    Frag a2f[2][3];                          // per-step A block, dbuf

    {   // prologue: B(steps 0,1), A(step0, mt 0..2)
        b2b[0].q = w2f[w * 64 + lane];
        b2b[1].q = w2f[(4 + w) * 64 + lane];
        #pragma unroll
        for (int mt = 0; mt < 3; ++mt) a2f[0][mt].q = aF[mt * 288];
    }

    #pragma unroll
    for (int s = 0; s < 20; ++s) {
        const int sb = s % 3, ab = s & 1, an = ab ^ 1;
        if (s < 18)
            b2b[(s + 2) % 3].q = w2f[((s + 2) * 4 + w) * 64 + lane];
        if (s < 19) {
            const int dkn = (s + 1) >> 2, iccn = (s + 1) & 3;
            #pragma unroll
            for (int mt = 0; mt < 3; ++mt)
                a2f[an][mt].q = aF[(mt * 32 + dkn) * 9 + iccn * 2];
        }
        __builtin_amdgcn_s_setprio(1);
        #pragma unroll
        for (int mt = 0; mt < 3; ++mt)
            acc2[mt] = __builtin_amdgcn_mfma_f32_32x32x16_f16(a2f[ab][mt].h, b2b[sb].h, acc2[mt], 0, 0, 0);
        __builtin_amdgcn_s_setprio(0);
    }

    // ---- epilogue: unscale (2^-10) + bias + relu + pool4 -> feat; fc7T ----
    float dot[7] = {0.f, 0.f, 0.f, 0.f, 0.f, 0.f, 0.f};
    {
        const float b2v = b2[w * 32 + lq];
        #pragma unroll
        for (int mt = 0; mt < 3; ++mt) {
            #pragma unroll
            for (int q = 0; q < 4; ++q) {
                float s = 0.f;
                #pragma unroll
                for (int r4 = 0; r4 < 4; ++r4)
                    s += fmaxf(acc2[mt][q*4+r4] * 0.0009765625f + b2v, 0.f);
                s *= 0.25f;
                const int fq = mt * 8 + 2 * q + hi;
                const float* fp = fc7 + fq * 1024 + w * 32 + lq;
                float f[7];
                #pragma unroll
                for (int j = 0; j < 7; ++j) f[j] = fp[j * 128];
                #pragma unroll
                for (int j = 0; j < 7; ++j) dot[j] += s * f[j];
            }
        }
    }

    #pragma unroll
    for (int j = 0; j < 7; ++j) {
        float s = dot[j];
        #pragma unroll
        for (int off = 32; off; off >>= 1) s += __shfl_down(s, off);
        if (lane == 0) red[w * 8 + j] = s;
    }
    __syncthreads();
    if (t < 7) {
        float s = red[t] + red[8 + t] + red[16 + t] + red[24 + t];
        s += (t < 6) ? fc_b[t] : taubp[0];
        params[(size_t)b * 8 + t] = s;
    }
}

// ---------------------------------------------------------------------------
// Kernel 2: DMP rollout — 1 thread per batch element (all lanes busy).
// ---------------------------------------------------------------------------
__global__ void rollout_kernel(const float* __restrict__ params,
                               const float* __restrict__ y0,
                               float* __restrict__ out) {
    const int b = blockIdx.x * 256 + threadIdx.x;
    const float* p = params + (size_t)b * 8;
    const float goal = p[0];
    const float w0 = p[1], w1 = p[2], w2 = p[3], w3 = p[4], w4 = p[5];
    const float tau = p[6];
    const float y0v = y0[b];

    const float c0 = 1.0f;
    const float c1 = 0.77880078307140486825f;
    const float c2 = 0.60653065971263342360f;
    const float c3 = 0.47236655274101470714f;
    const float c4 = 0.36787944117144232160f;
    const float inv2s = -0.5f / 11.180339887498949f;
    const float e0 = inv2s * c0, e1 = inv2s * c1, e2 = inv2s * c2,
                e3 = inv2s * c3, e4 = inv2s * c4;

    float x = 1.0f, y = y0v, z = 0.01f * tau;
    const float td = tau * 0.01f;
    const float gmy0 = goal - y0v;
    float* ob = out + (size_t)b * 101;
    ob[0] = y0v;
    for (int s = 1; s <= 100; ++s) {
        x = x - x * td;
        const float d0 = x - c0, d1 = x - c1, d2 = x - c2, d3 = x - c3, d4 = x - c4;
        const float p0 = __expf(e0 * d0 * d0);
        const float p1 = __expf(e1 * d1 * d1);
        const float p2 = __expf(e2 * d2 * d2);
        const float p3 = __expf(e3 * d3 * d3);
        const float p4 = __expf(e4 * d4 * d4);
        const float den = p0 + p1 + p2 + p3 + p4;
        const float num = w0 * p0 + w1 * p1 + w2 * p2 + w3 * p3 + w4 * p4;
        const float fx = (num / den) * x * gmy0;
        const float dz = 25.0f * (6.25f * (goal - y) - z) + fx;
        const float dy = z;
        y += dy * td;
        z += dz * td;
        ob[s] = y;
    }
}

extern "C" void kernel_launch(void* const* d_in, const int* in_sizes, int n_in,
                              void* d_out, int out_size, void* d_ws, size_t ws_size,
                              hipStream_t stream) {
    const float* input = (const float*)d_in[0];
    const float* y0    = (const float*)d_in[1];
    const float* w1    = (const float*)d_in[2];
    const float* b1    = (const float*)d_in[3];
    const float* w2    = (const float*)d_in[4];
    const float* b2    = (const float*)d_in[5];
    const float* fc_w  = (const float*)d_in[6];
    const float* fc_b  = (const float*)d_in[7];
    const float* L_w   = (const float*)d_in[8];
    const float* L_b   = (const float*)d_in[9];
    float* out = (float*)d_out;

    float* ws      = (float*)d_ws;
    float* fc7     = ws;                          // 24576 f (fc7T layout)
    float* taub    = ws + 24576;                  // pad to 64
    float* params  = ws + 24640;                  // 32768 f
    unsigned* wfrag1 = (unsigned*)(ws + 57408);   // 1536 u32 (pad to 4096)
    unsigned* wfrag2 = wfrag1 + 4096;             // 20480 u32

    const int B = in_sizes[1];                    // 4096

    precompute_kernel<<<107, 512, 0, stream>>>(w1, w2, fc_w, fc_b, L_w, L_b,
                                               fc7, taub, wfrag1, wfrag2);
    fused_kernel<<<B, 256, 0, stream>>>(input, b1, b2, wfrag1, wfrag2,
                                        fc7, fc_b, taub, params);
    rollout_kernel<<<B / 256, 256, 0, stream>>>(params, y0, out);
}

// Round 20
// 84.013 us; speedup vs baseline: 1.3329x; 1.0177x over previous
//
#include <hip/hip_runtime.h>
#include <math.h>

// ---------------------------------------------------------------------------
// B=4096. conv1 (64,5,7) pad3 + relu + pool4 -> h1 (64,96)
//         conv2 (128,64,5) pad2 + relu + pool4 -> feat (128,24)
//         fc: only cols 0..5 of (404,3072) + tau = feat·(L_w@fc_w) + const.
// Precision: conv1 = 1-term fp16 (A=f16(input), B=f16(1024*w1));
// conv2 = 1-term fp16 (A=f16(h1), B=f16(1024*w2)); epilogues unscale 2^-10.
// Measured absmax 128 vs threshold 460.8.
// All MFMAs v_mfma_f32_32x32x16_f16.
// C/D (m74/m101): col=lane&31(oc), row=(reg&3)+8*(reg>>2)+4*(lane>>5) ->
// reg-quads = 4 consecutive pos -> pool4 in-register.
// R20: unbundle R17 — KEEP 3-deep B prefetch + halo-only zeroing; REVERT
// staging to scalar loads (R17's float4 staging caused 4.5MB scratch spill
// + 737K bank-conflict cycles; scalar had neither). Last low-risk increment.
// ---------------------------------------------------------------------------

typedef _Float16 f16x8 __attribute__((ext_vector_type(8)));
typedef float f32x4  __attribute__((ext_vector_type(4)));
typedef float f32x16 __attribute__((ext_vector_type(16)));
typedef int   i32x4  __attribute__((ext_vector_type(4)));

union Frag { int u[4]; i32x4 q; f16x8 h; };
union H16 { _Float16 hf; unsigned short us; };

__device__ __forceinline__ unsigned short f16_rne(float f) {
    H16 c; c.hf = (_Float16)f; return c.us;
}

#define ZERO16 {0.f,0.f,0.f,0.f,0.f,0.f,0.f,0.f,0.f,0.f,0.f,0.f,0.f,0.f,0.f,0.f}

// ---------------------------------------------------------------------------
// Kernel 0 (512 thr, 107 blocks): fc7T (0..95), taub+wfrag1 (96),
// wfrag2 (97..106).
//  fc7T: [fq24][j8][oc128] f32; j0..5 = fc_w cols, j6 = L_w@fc_w, j7 = 0
//  wfrag1: [ks3][nt2][lane64][4u32] f16 of 1024*w1;
//          k'=ks*16+(lane>>5)*8+j -> ic=k'>>3, dk=k'&7 (ic==5 -> zero)
//  wfrag2: [step20][nt4][lane64][4u32] f16 of 1024*w2; step=dk*4+icc;
//          k_ic=icc*16+(lane>>5)*8+j
// ---------------------------------------------------------------------------
__global__ void precompute_kernel(const float* __restrict__ w1,
                                  const float* __restrict__ w2,
                                  const float* __restrict__ fc_w,
                                  const float* __restrict__ fc_b,
                                  const float* __restrict__ L_w,
                                  const float* __restrict__ L_b,
                                  float* __restrict__ fc7,
                                  float* __restrict__ taub,
                                  unsigned* __restrict__ wfrag1,
                                  unsigned* __restrict__ wfrag2) {
    const int t = threadIdx.x, bb = blockIdx.x;
    if (bb < 96) {
        __shared__ float part[15][32];
        const int k = bb * 32 + (t & 31), jc = t >> 5;       // jc 0..15
        const int j0 = jc * 26;
        float s = 0.f;
        #pragma unroll 8
        for (int j = j0; j < j0 + 26 && j < 404; ++j)
            s += L_w[j] * fc_w[j * 3072 + k];
        if (jc) part[jc - 1][t & 31] = s;
        __syncthreads();
        if (jc == 0) {
            const int kk = t & 31;
            const int oc = k / 24, fq = k - oc * 24;
            float r[8];
            #pragma unroll
            for (int j = 0; j < 6; ++j) r[j] = fc_w[j * 3072 + k];
            float tv = s;
            #pragma unroll
            for (int j = 0; j < 15; ++j) tv += part[j][kk];
            r[6] = tv; r[7] = 0.f;
            #pragma unroll
            for (int j = 0; j < 8; ++j) fc7[fq * 1024 + j * 128 + oc] = r[j];
        }
    } else if (bb == 96) {
        if (t < 64) {
            float s = 0.f;
            for (int j = t; j < 404; j += 64) s += L_w[j] * fc_b[j];
            #pragma unroll
            for (int off = 32; off; off >>= 1) s += __shfl_down(s, off);
            if (t == 0) taub[0] = s + L_b[0];
        }
        if (t < 384) {                              // conv1 frags (f16 1-term)
            const int lane = t & 63, nt = (t >> 6) & 1, ks = t >> 7;  // 0..2
            const int oc = nt * 32 + (lane & 31);
            unsigned short h[8];
            #pragma unroll
            for (int j = 0; j < 8; ++j) {
                const int kp = ks * 16 + (lane >> 5) * 8 + j;  // k' = ic*8+dk
                const int ic = kp >> 3, dk = kp & 7;
                const float v = (ic < 5 && dk < 7)
                              ? w1[oc * 35 + ic * 7 + dk] * 1024.0f : 0.f;
                h[j] = f16_rne(v);
            }
            #pragma unroll
            for (int wj = 0; wj < 4; ++wj)
                wfrag1[t * 4 + wj] = ((unsigned)h[2 * wj + 1] << 16) | h[2 * wj];
        }
    } else {                                        // conv2 frags: 5120 items
        const int i = (bb - 97) * 512 + t;
        const int lane = i & 63, nt = (i >> 6) & 3, step = i >> 8;   // 0..19
        const int oc = nt * 32 + (lane & 31);
        const int dk = step >> 2, icc = step & 3;
        unsigned short h[8];
        #pragma unroll
        for (int j = 0; j < 8; ++j) {
            const int ic = icc * 16 + (lane >> 5) * 8 + j;  // k = ic
            const float v = w2[oc * 320 + ic * 5 + dk] * 1024.0f;
            h[j] = f16_rne(v);
        }
        #pragma unroll
        for (int wj = 0; wj < 4; ++wj)
            wfrag2[i * 4 + wj] = ((unsigned)h[2 * wj + 1] << 16) | h[2 * wj];
    }
}

// ---------------------------------------------------------------------------
// Kernel 1: fused conv1+conv2+fc, one batch per block, 5 blocks/CU.
// LDS (22368 B): lds_in u32[5][392] = zero-extended f16(input) (halo zero),
//   h1f fp16[100][72] (rows 0,1,98,99 halo-zero), red f32[32].
// ---------------------------------------------------------------------------
__global__ __launch_bounds__(256, 5) void fused_kernel(
    const float* __restrict__ input,
    const float* __restrict__ b1,
    const float* __restrict__ b2,
    const unsigned* __restrict__ wfrag1,
    const unsigned* __restrict__ wfrag2,
    const float* __restrict__ fc7,
    const float* __restrict__ fc_b,
    const float* __restrict__ taubp,
    float* __restrict__ params)
{
    __shared__ unsigned lds_in[1960];                       // [5][392]
    __shared__ __align__(16) unsigned short h1f[7200];      // [100][72]
    __shared__ float red[32];

    const int t = threadIdx.x, b = blockIdx.x;
    const int lane = t & 63, w = t >> 6;
    const int lq = lane & 31, hi = lane >> 5;

    // ---- halo-only zeroing (disjoint from staging writes -> one barrier) --
    if (t < 40) {            // lds_in halos: cols 0..2, 387..391 x 5 rows
        const int r = t >> 3, c = t & 7;
        lds_in[r * 392 + ((c < 3) ? c : 384 + c)] = 0u;
    }
    if (t >= 64 && t < 208) {  // h1f halo rows 0,1,98,99 (144 words)
        const int i = t - 64;
        const int r = i / 36, wd = i - r * 36;
        const int row = (r < 2) ? r : 96 + r;
        ((unsigned*)h1f)[row * 36 + wd] = 0u;
    }
    // ---- stage input as zero-extended f16, scalar loads (no spill) ----
    const float* inb = input + (size_t)b * 1920;
    for (int i = t; i < 1920; i += 256) {
        const int ic = i / 384, x = i - ic * 384;
        lds_in[ic * 392 + 3 + x] = (unsigned)f16_rne(inb[i]);
    }
    __syncthreads();

    // ------------- conv1: C[pos=384][oc=64], K'=48 (3 ks of 16) -------------
    const i32x4* w1f = (const i32x4*)wfrag1;
    Frag c1b[3][2];                          // [ks][nt] — 24 VGPR
    #pragma unroll
    for (int ks = 0; ks < 3; ++ks)
        #pragma unroll
        for (int nt = 0; nt < 2; ++nt)
            c1b[ks][nt].q = w1f[(ks * 2 + nt) * 64 + lane];
    float b1v[2];
    #pragma unroll
    for (int nt = 0; nt < 2; ++nt) b1v[nt] = b1[nt * 32 + lq];

    unsigned pbuf[2][8];
    {   // prologue: (m=0, ks=0): ic = hi
        const unsigned* src = lds_in + hi * 392 + (w * 3) * 32 + lq;
        #pragma unroll
        for (int j = 0; j < 8; ++j) pbuf[0][j] = src[j];
    }
    #pragma unroll
    for (int m = 0; m < 3; ++m) {
        const int mtile = w * 3 + m;
        f32x16 acc0 = ZERO16, acc1 = ZERO16;
        #pragma unroll
        for (int ks = 0; ks < 3; ++ks) {
            const int it = m * 3 + ks, cur = it & 1, nxt = cur ^ 1;
            if (it < 8) {
                const int nit = it + 1, nm = nit / 3, nks = nit % 3;
                const int rowoff = (nks == 2) ? 4 * 392 : (nks * 2 + hi) * 392;
                const unsigned* src = lds_in + rowoff + (w * 3 + nm) * 32 + lq;
                #pragma unroll
                for (int j = 0; j < 8; ++j) pbuf[nxt][j] = src[j];
            }
            Frag af;
            #pragma unroll
            for (int wj = 0; wj < 4; ++wj)
                af.u[wj] = __builtin_amdgcn_perm(pbuf[cur][2*wj+1], pbuf[cur][2*wj], 0x05040100u);
            if (ks == 2) {     // ic = ks*2+hi = 5 for hi=1: virtual zero row
                #pragma unroll
                for (int wj = 0; wj < 4; ++wj) af.u[wj] = hi ? 0 : af.u[wj];
            }
            __builtin_amdgcn_s_setprio(1);
            acc0 = __builtin_amdgcn_mfma_f32_32x32x16_f16(af.h, c1b[ks][0].h, acc0, 0, 0, 0);
            acc1 = __builtin_amdgcn_mfma_f32_32x32x16_f16(af.h, c1b[ks][1].h, acc1, 0, 0, 0);
            __builtin_amdgcn_s_setprio(0);
        }
        // unscale 2^-10 + bias + relu + pool4 -> f16 write
        #pragma unroll
        for (int q = 0; q < 4; ++q) {
            const int c = mtile * 8 + 2 * q + hi;
            {
                float s = 0.f;
                #pragma unroll
                for (int r4 = 0; r4 < 4; ++r4)
                    s += fmaxf(acc0[q*4+r4] * 0.0009765625f + b1v[0], 0.f);
                h1f[(c + 2) * 72 + lq] = f16_rne(0.25f * s);
            }
            {
                float s = 0.f;
                #pragma unroll
                for (int r4 = 0; r4 < 4; ++r4)
                    s += fmaxf(acc1[q*4+r4] * 0.0009765625f + b1v[1], 0.f);
                h1f[(c + 2) * 72 + 32 + lq] = f16_rne(0.25f * s);
            }
        }
    }
    __syncthreads();

    // ------ conv2: 20 k-steps (dk*4+icc), wave = ntile w, mtiles 0..2 ------
    f32x16 acc2[3] = {ZERO16, ZERO16, ZERO16};

    const i32x4* aF = (const i32x4*)(h1f + lq * 72 + hi * 8);
    const i32x4* w2f = (const i32x4*)wfrag2;
    Frag b2b[3];                             // B 3-deep rotation
    Frag a2f[2][3];                          // per-step A block, dbuf

    {   // prologue: B(steps 0,1), A(step0, mt 0..2)
        b2b[0].q = w2f[w * 64 + lane];
        b2b[1].q = w2f[(4 + w) * 64 + lane];
        #pragma unroll
        for (int mt = 0; mt < 3; ++mt) a2f[0][mt].q = aF[mt * 288];
    }

    #pragma unroll
    for (int s = 0; s < 20; ++s) {
        const int sb = s % 3, ab = s & 1, an = ab ^ 1;
        if (s < 18)
            b2b[(s + 2) % 3].q = w2f[((s + 2) * 4 + w) * 64 + lane];
        if (s < 19) {
            const int dkn = (s + 1) >> 2, iccn = (s + 1) & 3;
            #pragma unroll
            for (int mt = 0; mt < 3; ++mt)
                a2f[an][mt].q = aF[(mt * 32 + dkn) * 9 + iccn * 2];
        }
        __builtin_amdgcn_s_setprio(1);
        #pragma unroll
        for (int mt = 0; mt < 3; ++mt)
            acc2[mt] = __builtin_amdgcn_mfma_f32_32x32x16_f16(a2f[ab][mt].h, b2b[sb].h, acc2[mt], 0, 0, 0);
        __builtin_amdgcn_s_setprio(0);
    }

    // ---- epilogue: unscale (2^-10) + bias + relu + pool4 -> feat; fc7T ----
    float dot[7] = {0.f, 0.f, 0.f, 0.f, 0.f, 0.f, 0.f};
    {
        const float b2v = b2[w * 32 + lq];
        #pragma unroll
        for (int mt = 0; mt < 3; ++mt) {
            #pragma unroll
            for (int q = 0; q < 4; ++q) {
                float s = 0.f;
                #pragma unroll
                for (int r4 = 0; r4 < 4; ++r4)
                    s += fmaxf(acc2[mt][q*4+r4] * 0.0009765625f + b2v, 0.f);
                s *= 0.25f;
                const int fq = mt * 8 + 2 * q + hi;
                const float* fp = fc7 + fq * 1024 + w * 32 + lq;
                float f[7];
                #pragma unroll
                for (int j = 0; j < 7; ++j) f[j] = fp[j * 128];
                #pragma unroll
                for (int j = 0; j < 7; ++j) dot[j] += s * f[j];
            }
        }
    }

    #pragma unroll
    for (int j = 0; j < 7; ++j) {
        float s = dot[j];
        #pragma unroll
        for (int off = 32; off; off >>= 1) s += __shfl_down(s, off);
        if (lane == 0) red[w * 8 + j] = s;
    }
    __syncthreads();
    if (t < 7) {
        float s = red[t] + red[8 + t] + red[16 + t] + red[24 + t];
        s += (t < 6) ? fc_b[t] : taubp[0];
        params[(size_t)b * 8 + t] = s;
    }
}

// ---------------------------------------------------------------------------
// Kernel 2: DMP rollout — 1 thread per batch element (all lanes busy).
// ---------------------------------------------------------------------------
__global__ void rollout_kernel(const float* __restrict__ params,
                               const float* __restrict__ y0,
                               float* __restrict__ out) {
    const int b = blockIdx.x * 256 + threadIdx.x;
    const float* p = params + (size_t)b * 8;
    const float goal = p[0];
    const float w0 = p[1], w1 = p[2], w2 = p[3], w3 = p[4], w4 = p[5];
    const float tau = p[6];
    const float y0v = y0[b];

    const float c0 = 1.0f;
    const float c1 = 0.77880078307140486825f;
    const float c2 = 0.60653065971263342360f;
    const float c3 = 0.47236655274101470714f;
    const float c4 = 0.36787944117144232160f;
    const float inv2s = -0.5f / 11.180339887498949f;
    const float e0 = inv2s * c0, e1 = inv2s * c1, e2 = inv2s * c2,
                e3 = inv2s * c3, e4 = inv2s * c4;

    float x = 1.0f, y = y0v, z = 0.01f * tau;
    const float td = tau * 0.01f;
    const float gmy0 = goal - y0v;
    float* ob = out + (size_t)b * 101;
    ob[0] = y0v;
    for (int s = 1; s <= 100; ++s) {
        x = x - x * td;
        const float d0 = x - c0, d1 = x - c1, d2 = x - c2, d3 = x - c3, d4 = x - c4;
        const float p0 = __expf(e0 * d0 * d0);
        const float p1 = __expf(e1 * d1 * d1);
        const float p2 = __expf(e2 * d2 * d2);
        const float p3 = __expf(e3 * d3 * d3);
        const float p4 = __expf(e4 * d4 * d4);
        const float den = p0 + p1 + p2 + p3 + p4;
        const float num = w0 * p0 + w1 * p1 + w2 * p2 + w3 * p3 + w4 * p4;
        const float fx = (num / den) * x * gmy0;
        const float dz = 25.0f * (6.25f * (goal - y) - z) + fx;
        const float dy = z;
        y += dy * td;
        z += dz * td;
        ob[s] = y;
    }
}

extern "C" void kernel_launch(void* const* d_in, const int* in_sizes, int n_in,
                              void* d_out, int out_size, void* d_ws, size_t ws_size,
                              hipStream_t stream) {
    const float* input = (const float*)d_in[0];
    const float* y0    = (const float*)d_in[1];
    const float* w1    = (const float*)d_in[2];
    const float* b1    = (const float*)d_in[3];
    const float* w2    = (const float*)d_in[4];
    const float* b2    = (const float*)d_in[5];
    const float* fc_w  = (const float*)d_in[6];
    const float* fc_b  = (const float*)d_in[7];
    const float* L_w   = (const float*)d_in[8];
    const float* L_b   = (const float*)d_in[9];
    float* out = (float*)d_out;

    float* ws      = (float*)d_ws;
    float* fc7     = ws;                          // 24576 f (fc7T layout)
    float* taub    = ws + 24576;                  // pad to 64
    float* params  = ws + 24640;                  // 32768 f
    unsigned* wfrag1 = (unsigned*)(ws + 57408);   // 1536 u32 (pad to 4096)
    unsigned* wfrag2 = wfrag1 + 4096;             // 20480 u32

    const int B = in_sizes[1];                    // 4096

    precompute_kernel<<<107, 512, 0, stream>>>(w1, w2, fc_w, fc_b, L_w, L_b,
                                               fc7, taub, wfrag1, wfrag2);
    fused_kernel<<<B, 256, 0, stream>>>(input, b1, b2, wfrag1, wfrag2,
                                        fc7, fc_b, taub, params);
    rollout_kernel<<<B / 256, 256, 0, stream>>>(params, y0, out);
}